// Round 2
// baseline (148.350 us; speedup 1.0000x reference)
//
#include <hip/hip_runtime.h>
#include <math.h>

// Adder2D: out[n,co,h,w] = -sum_{ci,kh,kw} |x[n,ci,h+kh-1,w+kw-1] - w[co,ci,kh,kw]|
// x: [16,64,32,32] f32, w: [64,64,3,3] f32, out: [16,64,32,32] f32, pad=1 stride=1.
//
// R5: max occupancy. R4 post-mortem: true VALU issue ~29% (derived VALUBusy
// inflated ~2.3x by gfx94x formula), no pipe >30% busy -> latency-bound with
// only 4 waves/SIMD. Now: 1024-thread blocks, 4-way ci split (each 256-thread
// group computes 4 of the 16 staged planes per round), partials combined via
// LDS. Grid stays 512 -> 2 blocks/CU = 2048 threads/CU = 32 waves/CU =
// 8 waves/SIMD (hardware cap). Reduction buffer (24KB) aliases the dead
// x-tile so LDS stays 41.5KB/block and 2 blocks/CU fit.
// Inner loop / staging / layout identical to R4 (clean A/B on occupancy).

#define N_   16
#define CI_  64
#define CO_  64
#define HW_  32
#define CG   4      // co per thread
#define COB  8      // co per block
#define RG   8      // pixel rows per block
#define CIC  16     // ci planes staged per round
#define CPG  4      // ci planes computed per group per round
#define ROWS (RG + 2)
#define LW   36     // LDS row stride: col0 = left halo, 1..32 = data, 33 = right halo

#define XS_WORDS (CIC * ROWS * LW)        // 5760 words = 23040 B
#define WS_WORDS (CI_ * 9 * COB)          // 4608 words = 18432 B
#define SMEM_WORDS (XS_WORDS + WS_WORDS)  // 10368 words = 41472 B

__global__ __launch_bounds__(1024, 8) void adder2d_kernel(
    const float* __restrict__ x, const float* __restrict__ w,
    float* __restrict__ out)
{
    __shared__ __align__(16) float smem[SMEM_WORDS];
    float (*xs)[ROWS][LW] = (float (*)[ROWS][LW])smem;          // phase A
    float (*wsp)[9][COB]  = (float (*)[9][COB])(smem + XS_WORDS);
    float (*red)[256][8]  = (float (*)[256][8])smem;            // phase B: aliases xs
                                                                // (3*256*8 = 6144 <= 5760+... fits in 10368)

    const int tid   = threadIdx.x;
    const int u     = tid & 15;          // col-pair: pixels at cols 2u, 2u+1
    const int rl    = (tid >> 4) & 7;    // pixel row within block
    const int cosub = (tid >> 7) & 1;    // co half
    const int cig   = tid >> 8;          // ci group: 0..3
    const int r0    = blockIdx.x * RG;
    const int co0   = blockIdx.y * COB;
    const int n     = blockIdx.z;

    // ---- stage w once: w[co0+cl][ci][t] -> ws[ci][t][cl] ----
    for (int i = tid; i < WS_WORDS; i += 1024) {
        int cl  = i / (CI_ * 9);
        int rem = i - cl * (CI_ * 9);    // = ci*9 + t
        wsp[rem / 9][rem % 9][cl] = w[(co0 + cl) * (CI_ * 9) + rem];
    }
    // ---- zero xs once: halo cols (0,33) and OOB row slots stay zero
    //      forever; staging rewrites only in-bounds data cols ----
    for (int i = tid; i < XS_WORDS / 4; i += 1024)
        ((float4*)smem)[i] = float4{0.f, 0.f, 0.f, 0.f};

    float acc0[CG], acc1[CG];
#pragma unroll
    for (int j = 0; j < CG; ++j) { acc0[j] = 0.f; acc1[j] = 0.f; }

    const float* xn = x + (size_t)n * CI_ * HW_ * HW_;
    const int pbase = cig * CPG;

    for (int round = 0; round < CI_ / CIC; ++round) {
        const int cc0 = round * CIC;
        __syncthreads();   // protect LDS from previous round's readers
        // ---- stage CIC planes, rows r0-1..r0+8: 1280 float4 units ----
        for (int i = tid; i < CIC * ROWS * (HW_ / 4); i += 1024) {
            int plane = i / (ROWS * (HW_ / 4));
            int rem   = i - plane * (ROWS * (HW_ / 4));
            int rr    = rem >> 3;
            int f4    = rem & 7;
            int gr    = r0 - 1 + rr;
            if ((unsigned)gr < HW_) {
                float4 v = ((const float4*)(xn + (size_t)(cc0 + plane) * HW_ * HW_
                                            + gr * HW_))[f4];
                float* dst = &xs[plane][rr][1 + 4 * f4];   // data cols start at 1
                dst[0] = v.x; dst[1] = v.y; dst[2] = v.z; dst[3] = v.w;
            }
        }
        __syncthreads();

#pragma unroll
        for (int cil = 0; cil < CPG; ++cil) {
            const int pl = pbase + cil;
            const int ci = cc0 + pl;

            // 9 b128 broadcasts: wv[t][j] = w[co0+4*cosub+j][ci][t]
            float4 wv[9];
#pragma unroll
            for (int t = 0; t < 9; ++t)
                wv[t] = *(const float4*)&wsp[ci][t][cosub * CG];

            // x patch for 2 pixels: rows rl..rl+2, storage cols 2u..2u+3
            // (= real cols 2u-1..2u+2, halos pre-zeroed). Aligned 2x float2.
            float4 xv[3];
#pragma unroll
            for (int kh = 0; kh < 3; ++kh) {
                const float* row = &xs[pl][rl + kh][2 * u];
                float2 lo = *(const float2*)&row[0];
                float2 hi = *(const float2*)&row[2];
                xv[kh] = float4{lo.x, lo.y, hi.x, hi.y};
            }

            // 144 VALU: 2 pix x 4 co x 9 taps, sub + add-with-|.|-modifier
#pragma unroll
            for (int kh = 0; kh < 3; ++kh)
#pragma unroll
                for (int kw = 0; kw < 3; ++kw) {
                    const int t = kh * 3 + kw;
                    float xa = (kw == 0) ? xv[kh].x : ((kw == 1) ? xv[kh].y : xv[kh].z);
                    float xb = (kw == 0) ? xv[kh].y : ((kw == 1) ? xv[kh].z : xv[kh].w);
                    const float* wj = (const float*)&wv[t];
#pragma unroll
                    for (int j = 0; j < CG; ++j) {
                        acc0[j] += fabsf(xa - wj[j]);
                        acc1[j] += fabsf(xb - wj[j]);
                    }
                }
        }
    }

    // ---- combine the four ci-group partials (red aliases dead xs) ----
    __syncthreads();   // all xs/ws readers done before overwrite
    if (cig != 0) {
        int t = tid & 255;
        *(float4*)&red[cig - 1][t][0] = float4{acc0[0], acc0[1], acc0[2], acc0[3]};
        *(float4*)&red[cig - 1][t][4] = float4{acc1[0], acc1[1], acc1[2], acc1[3]};
    }
    __syncthreads();
    if (cig == 0) {
#pragma unroll
        for (int g = 0; g < 3; ++g) {
            float4 ra = *(const float4*)&red[g][tid][0];
            float4 rb = *(const float4*)&red[g][tid][4];
            acc0[0] += ra.x; acc0[1] += ra.y; acc0[2] += ra.z; acc0[3] += ra.w;
            acc1[0] += rb.x; acc1[1] += rb.y; acc1[2] += rb.z; acc1[3] += rb.w;
        }
        float* op = out + (((size_t)n * CO_ + co0 + cosub * CG) * HW_ + (r0 + rl)) * HW_ + 2 * u;
#pragma unroll
        for (int j = 0; j < CG; ++j)
            *(float2*)&op[(size_t)j * HW_ * HW_] = float2{-acc0[j], -acc1[j]};
    }
}

extern "C" void kernel_launch(void* const* d_in, const int* in_sizes, int n_in,
                              void* d_out, int out_size, void* d_ws, size_t ws_size,
                              hipStream_t stream) {
    const float* x  = (const float*)d_in[0];
    const float* wp = (const float*)d_in[1];
    float* out      = (float*)d_out;
    dim3 grid(HW_ / RG, CO_ / COB, N_);   // (4, 8, 16) = 512 blocks
    adder2d_kernel<<<grid, 1024, 0, stream>>>(x, wp, out);
}

// Round 4
// 103.103 us; speedup vs baseline: 1.4388x; 1.4388x over previous
//
#include <hip/hip_runtime.h>
#include <math.h>

// Adder2D: out[n,co,h,w] = -sum_{ci,kh,kw} |x[n,ci,h+kh-1,w+kw-1] - w[co,ci,kh,kw]|
// x: [16,64,32,32] f32, w: [64,64,3,3] f32, out: [16,64,32,32] f32, pad=1 stride=1.
//
// R6-retry: previous submission failed at the container level (infra), no
// kernel signal. Source re-audited (guarded global loads, disjoint LDS
// regions, uniform barriers) and resubmitted unchanged.
//
// R6: occupancy WITHOUT the register crunch. R5 post-mortem: launch_bounds
// (1024,8) forced VGPR=32 -> massive scratch spill (WRITE_SIZE 4->244MB),
// 110us. The occupancy mechanism itself worked (75%). Now: same R4 inner
// body (44 VGPR), but COB=4 co per block -> 512-thread blocks (128 output
// threads x 4 ci-groups), grid (4,16,16)=1024. LDS = 31.5KB -> 4 blocks/CU
// by LDS, 32 waves/CU by slots; launch_bounds(512,4) caps VGPR at 128 so
// the allocator is free; emitted ~48 <= 64 means HW grants 8 waves/SIMD at
// runtime. 4 independent barrier groups/CU stagger staging vs compute.

#define N_   16
#define CI_  64
#define CO_  64
#define HW_  32
#define CG   4      // co per thread (= all of COB)
#define COB  4      // co per block
#define RG   8      // pixel rows per block
#define CIC  16     // ci planes staged per round
#define CPG  4      // ci planes computed per group per round
#define ROWS (RG + 2)
#define LW   36     // LDS row stride: col0 = left halo, 1..32 = data, 33 = right halo

#define XS_WORDS (CIC * ROWS * LW)        // 5760 words = 23040 B
#define WS_WORDS (CI_ * 9 * COB)          // 2304 words =  9216 B
#define SMEM_WORDS (XS_WORDS + WS_WORDS)  // 8064 words = 32256 B

__global__ __launch_bounds__(512, 4) void adder2d_kernel(
    const float* __restrict__ x, const float* __restrict__ w,
    float* __restrict__ out)
{
    __shared__ __align__(16) float smem[SMEM_WORDS];
    float (*xs)[ROWS][LW] = (float (*)[ROWS][LW])smem;           // phase A
    float (*wsp)[9][COB]  = (float (*)[9][COB])(smem + XS_WORDS);
    float (*red)[128][8]  = (float (*)[128][8])smem;             // phase B: aliases xs
                                                                 // 3*128*8 = 3072 <= 5760 ok

    const int tid = threadIdx.x;
    const int u   = tid & 15;            // col-pair: pixels at cols 2u, 2u+1
    const int rl  = (tid >> 4) & 7;      // pixel row within block
    const int cig = tid >> 7;            // ci group: 0..3
    const int r0  = blockIdx.x * RG;
    const int co0 = blockIdx.y * COB;
    const int n   = blockIdx.z;

    // ---- stage w once: w[co0+cl][ci][t] -> ws[ci][t][cl] ----
    for (int i = tid; i < WS_WORDS; i += 512) {
        int cl  = i / (CI_ * 9);
        int rem = i - cl * (CI_ * 9);    // = ci*9 + t
        wsp[rem / 9][rem % 9][cl] = w[(co0 + cl) * (CI_ * 9) + rem];
    }
    // ---- zero xs once: halo cols (0,33) and OOB row slots stay zero
    //      forever; staging rewrites only in-bounds data cols ----
    for (int i = tid; i < XS_WORDS / 4; i += 512)
        ((float4*)smem)[i] = float4{0.f, 0.f, 0.f, 0.f};

    float acc0[CG], acc1[CG];
#pragma unroll
    for (int j = 0; j < CG; ++j) { acc0[j] = 0.f; acc1[j] = 0.f; }

    const float* xn = x + (size_t)n * CI_ * HW_ * HW_;
    const int pbase = cig * CPG;

    for (int round = 0; round < CI_ / CIC; ++round) {
        const int cc0 = round * CIC;
        __syncthreads();   // protect LDS from previous round's readers
        // ---- stage CIC planes, rows r0-1..r0+8: 1280 float4 units ----
        for (int i = tid; i < CIC * ROWS * (HW_ / 4); i += 512) {
            int plane = i / (ROWS * (HW_ / 4));
            int rem   = i - plane * (ROWS * (HW_ / 4));
            int rr    = rem >> 3;
            int f4    = rem & 7;
            int gr    = r0 - 1 + rr;
            if ((unsigned)gr < HW_) {
                float4 v = ((const float4*)(xn + (size_t)(cc0 + plane) * HW_ * HW_
                                            + gr * HW_))[f4];
                float* dst = &xs[plane][rr][1 + 4 * f4];   // data cols start at 1
                dst[0] = v.x; dst[1] = v.y; dst[2] = v.z; dst[3] = v.w;
            }
        }
        __syncthreads();

#pragma unroll
        for (int cil = 0; cil < CPG; ++cil) {
            const int pl = pbase + cil;
            const int ci = cc0 + pl;

            // 9 b128 broadcasts: wv[t][j] = w[co0+j][ci][t]
            float4 wv[9];
#pragma unroll
            for (int t = 0; t < 9; ++t)
                wv[t] = *(const float4*)&wsp[ci][t][0];

            // x patch for 2 pixels: rows rl..rl+2, storage cols 2u..2u+3
            // (= real cols 2u-1..2u+2, halos pre-zeroed). Aligned 2x float2.
            float4 xv[3];
#pragma unroll
            for (int kh = 0; kh < 3; ++kh) {
                const float* row = &xs[pl][rl + kh][2 * u];
                float2 lo = *(const float2*)&row[0];
                float2 hi = *(const float2*)&row[2];
                xv[kh] = float4{lo.x, lo.y, hi.x, hi.y};
            }

            // 144 VALU: 2 pix x 4 co x 9 taps, sub + add-with-|.|-modifier
#pragma unroll
            for (int kh = 0; kh < 3; ++kh)
#pragma unroll
                for (int kw = 0; kw < 3; ++kw) {
                    const int t = kh * 3 + kw;
                    float xa = (kw == 0) ? xv[kh].x : ((kw == 1) ? xv[kh].y : xv[kh].z);
                    float xb = (kw == 0) ? xv[kh].y : ((kw == 1) ? xv[kh].z : xv[kh].w);
                    const float* wj = (const float*)&wv[t];
#pragma unroll
                    for (int j = 0; j < CG; ++j) {
                        acc0[j] += fabsf(xa - wj[j]);
                        acc1[j] += fabsf(xb - wj[j]);
                    }
                }
        }
    }

    // ---- combine the four ci-group partials (red aliases dead xs) ----
    __syncthreads();   // all xs/ws readers done before overwrite
    if (cig != 0) {
        int t = tid & 127;
        *(float4*)&red[cig - 1][t][0] = float4{acc0[0], acc0[1], acc0[2], acc0[3]};
        *(float4*)&red[cig - 1][t][4] = float4{acc1[0], acc1[1], acc1[2], acc1[3]};
    }
    __syncthreads();
    if (cig == 0) {
#pragma unroll
        for (int g = 0; g < 3; ++g) {
            float4 ra = *(const float4*)&red[g][tid][0];
            float4 rb = *(const float4*)&red[g][tid][4];
            acc0[0] += ra.x; acc0[1] += ra.y; acc0[2] += ra.z; acc0[3] += ra.w;
            acc1[0] += rb.x; acc1[1] += rb.y; acc1[2] += rb.z; acc1[3] += rb.w;
        }
        float* op = out + (((size_t)n * CO_ + co0) * HW_ + (r0 + rl)) * HW_ + 2 * u;
#pragma unroll
        for (int j = 0; j < CG; ++j)
            *(float2*)&op[(size_t)j * HW_ * HW_] = float2{-acc0[j], -acc1[j]};
    }
}

extern "C" void kernel_launch(void* const* d_in, const int* in_sizes, int n_in,
                              void* d_out, int out_size, void* d_ws, size_t ws_size,
                              hipStream_t stream) {
    const float* x  = (const float*)d_in[0];
    const float* wp = (const float*)d_in[1];
    float* out      = (float*)d_out;
    dim3 grid(HW_ / RG, CO_ / COB, N_);   // (4, 16, 16) = 1024 blocks
    adder2d_kernel<<<grid, 512, 0, stream>>>(x, wp, out);
}